// Round 12
// baseline (118.897 us; speedup 1.0000x reference)
//
#include <hip/hip_runtime.h>

#define NSEG 8192           // faces per set
#define NPTS (3 * NSEG)     // 24576 unified points [S | T | R]
#define NSUP 96             // 256-point super-tiles (32 per segment)
#define NXB  192            // 2 blocks (128 i-rows each) per super-tile
#define NYG  13             // y-groups: g<12 -> Y=4g..4g+3; g==12 -> Y=48

typedef short bf16x8 __attribute__((ext_vector_type(8)));   // 8 bf16 (4 VGPRs)
typedef float f32x16 __attribute__((ext_vector_type(16)));  // 16 fp32 acc
typedef unsigned short u16;

__device__ __forceinline__ u16 f2bf(float x) {              // RNE f32 -> bf16 bits
    unsigned u = __builtin_bit_cast(unsigned, x);
    return (u16)((u + 0x7FFFu + ((u >> 16) & 1u)) >> 16);
}
__device__ __forceinline__ float bf2f(u16 h) {
    unsigned u = ((unsigned)h) << 16;
    return __builtin_bit_cast(float, u);
}

__device__ __forceinline__ void compute_point(
    int seg, int f,
    const float* __restrict__ sv, const int* __restrict__ si,
    const float* __restrict__ tv, const int* __restrict__ ti,
    const float* __restrict__ rn, const float* __restrict__ rc,
    float& cx, float& cy, float& cz, float& nx, float& ny, float& nz)
{
    if (seg == 2) {
        nx = rn[3*f];   ny = rn[3*f+1]; nz = rn[3*f+2];
        cx = rc[3*f];   cy = rc[3*f+1]; cz = rc[3*f+2];
    } else {
        const float* v  = (seg == 0) ? sv : tv;
        const int*   nd = (seg == 0) ? si : ti;
        int i0 = nd[3*f], i1 = nd[3*f+1], i2 = nd[3*f+2];
        float ax = v[3*i0], ay = v[3*i0+1], az = v[3*i0+2];
        float bx = v[3*i1], by = v[3*i1+1], bz = v[3*i1+2];
        float gx = v[3*i2], gy = v[3*i2+1], gz = v[3*i2+2];
        float ux = ax-bx, uy = ay-by, uz = az-bz;
        float wx = gx-bx, wy = gy-by, wz = gz-bz;
        nx = 0.5f*(uy*wz - uz*wy);
        ny = 0.5f*(uz*wx - ux*wz);
        nz = 0.5f*(ux*wy - uy*wx);
        cx = (ax+bx+gx)*(1.0f/3.0f);
        cy = (ay+by+gy)*(1.0f/3.0f);
        cz = (az+bz+gz)*(1.0f/3.0f);
    }
}

// Feature rows (K=16 bf16), hi/lo split: t = A_t . B_t = 1+|ci-cj|^2 (~1e-3 abs err).
// 2-way split grid (R10 fix: 96 blocks was 0.375/CU, pure latency-bound):
// blocks 0..95 build A-records {at,an}, 96..191 build B-records {bt,bn}.
__global__ void setup_feats(const float* __restrict__ sv, const int* __restrict__ si,
                            const float* __restrict__ tv, const int* __restrict__ ti,
                            const float* __restrict__ rn, const float* __restrict__ rc,
                            u16* __restrict__ ws, float* __restrict__ out) {
    int gid = blockIdx.x * 256 + threadIdx.x;
    if (gid == 0) out[0] = 0.0f;        // d_out poisoned 0xAA before every launch
    const int rec = (gid >= NPTS);      // block-uniform (96 blocks per record kind)
    const int p   = rec ? gid - NPTS : gid;
    int seg = p >> 13, f = p & (NSEG - 1);
    float cx, cy, cz, nx, ny, nz;
    compute_point(seg, f, sv, si, tv, ti, rn, rc, cx, cy, cz, nx, ny, nz);

    const u16 ONE = 0x3F80;
    float s = cx*cx + cy*cy + cz*cz;
    u16 chx = f2bf(cx), chy = f2bf(cy), chz = f2bf(cz);
    u16 clx = f2bf(cx - bf2f(chx)), cly = f2bf(cy - bf2f(chy)), clz = f2bf(cz - bf2f(chz));
    u16 sh  = f2bf(s);
    u16 sl  = f2bf(s - bf2f(sh));
    u16 nhx = f2bf(nx), nhy = f2bf(ny), nhz = f2bf(nz);
    u16 nlx = f2bf(nx - bf2f(nhx)), nly = f2bf(ny - bf2f(nhy)), nlz = f2bf(nz - bf2f(nhz));

    bf16x8* A8 = (bf16x8*)ws;            // A-record: frags [at0 at1 an0 an1] per point
    bf16x8* B8 = A8 + (size_t)NPTS*4;    // B-record: frags [bt0 bt1 bn0 bn1] per point
    u16 r0[16], r1[16];
    if (!rec) {
        u16 at[16] = {chx,chy,chz, clx,cly,clz, chx,chy,chz, sh, sl, ONE, ONE, ONE, 0, 0};
        u16 an[16] = {nhx,nhy,nhz, nlx,nly,nlz, nhx,nhy,nhz, 0,0,0,0,0,0,0};
        #pragma unroll
        for (int k = 0; k < 16; ++k) { r0[k] = at[k]; r1[k] = an[k]; }
    } else {
        u16 m2hx = f2bf(-2.0f*bf2f(chx)), m2hy = f2bf(-2.0f*bf2f(chy)), m2hz = f2bf(-2.0f*bf2f(chz));
        u16 m2lx = f2bf(-2.0f*bf2f(clx)), m2ly = f2bf(-2.0f*bf2f(cly)), m2lz = f2bf(-2.0f*bf2f(clz));
        u16 bt[16] = {m2hx,m2hy,m2hz, m2hx,m2hy,m2hz, m2lx,m2ly,m2lz, ONE, ONE, sh, sl, ONE, 0, 0};
        u16 bn[16] = {nhx,nhy,nhz, nhx,nhy,nhz, nlx,nly,nlz, 0,0,0,0,0,0,0};
        #pragma unroll
        for (int k = 0; k < 16; ++k) { r0[k] = bt[k]; r1[k] = bn[k]; }
    }
    bf16x8* dst = rec ? B8 : A8;
    bf16x8 v0, v1, v2, v3;
    #pragma unroll
    for (int k = 0; k < 8; ++k) { v0[k] = (short)r0[k]; v1[k] = (short)r0[k+8];
                                  v2[k] = (short)r1[k]; v3[k] = (short)r1[k+8]; }
    dst[(size_t)p*4+0] = v0; dst[(size_t)p*4+1] = v1;
    dst[(size_t)p*4+2] = v2; dst[(size_t)p*4+3] = v3;
}

// Symmetric-pair kernel, 3-stage software pipeline (R11): iteration k issues
// MFMA(k) on frags loaded at k-1, loads frags k+1, then runs epilogue(k-1) —
// epilogue VALU (incl. AGPR readback) overlaps MFMA latency and load latency.
// Wrapped map over 256-pt super-tiles: (I,J) = (X, (X+Y)%96); mult = 2 except
// Y==0 (diagonal, once) and Y==48 (hit from both ends) -> 96+96+96*47*2 = 96^2. ✓
// Block = 256 thr = 4 waves x 32 i-rows (i-base = X*256 + (bx&1)*128);
// flattened loop over (4 Y values) x (8 j-tiles) = 32 tiles (g==12: 8 tiles).
__launch_bounds__(256, 3)
__global__ void energy_mfma(const u16* __restrict__ ws, float* __restrict__ out) {
    const int tid  = threadIdx.x;
    const int lane = tid & 63, wid = tid >> 6;
    const int half = lane >> 5, r32 = lane & 31;

    const int bx = blockIdx.x;                // 0..191
    const int X  = bx >> 1;                   // super-tile row 0..95
    const int g  = blockIdx.y;                // 0..12
    const int y0   = (g < 12) ? 4*g : 48;
    const int total = ((g < 12) ? 4 : 1) * 8; // tiles this block
    const int gi = X >> 5;                    // 32 super-tiles per segment

    // block-uniform weight row W[gi][*]
    const float w0 = (gi == 0) ? 1.8f : (gi == 1 ? -0.8f : -1.0f);
    const float w1 = (gi == 0) ? -0.8f : (gi == 1 ? 1.8f : -1.0f);
    const float w2 = (gi == 2) ? 2.0f : -1.0f;

    const bf16x8* A8 = (const bf16x8*)ws;
    const bf16x8* B8 = A8 + (size_t)NPTS*4;

    // one persistent 32-row i-tile per wave
    const int pi = X*256 + (bx & 1)*128 + wid*32 + r32;
    const bf16x8 at = A8[pi*4 + half];
    const bf16x8 an = A8[pi*4 + 2 + half];

    f32x16 Z;
    #pragma unroll
    for (int k = 0; k < 16; ++k) Z[k] = 0.0f;

    const int lofs = r32*4 + half;            // per-lane frag offset within a j-tile

    // per-tile uniform helpers (SALU): J(idx), offset(idx), w(idx)
    #define TILE_OFS(idx, Jv)  ({ int _y = y0 + ((idx) >> 3);                      \
                                  int _J = X + _y; if (_J >= NSUP) _J -= NSUP;     \
                                  Jv = _J; _J*1024 + ((idx) & 7)*128 + lofs; })
    #define TILE_W(idx, Jv)    ({ int _y = y0 + ((idx) >> 3);                      \
                                  float _m = (_y == 0 || _y == 48) ? 1.0f : 2.0f;  \
                                  int _gj = (Jv) >> 5;                             \
                                  ((_gj == 0) ? w0 : (_gj == 1 ? w1 : w2)) * _m; })

    // ---- pipeline prologue ----
    int J0; int o0 = TILE_OFS(0, J0);
    bf16x8 btf = B8[o0], bnf = B8[o0 + 2];                 // frags tile 0
    f32x16 ct_p = __builtin_amdgcn_mfma_f32_32x32x16_bf16(at, btf, Z, 0, 0, 0);
    f32x16 cn_p = __builtin_amdgcn_mfma_f32_32x32x16_bf16(an, bnf, Z, 0, 0, 0);
    float w_p = TILE_W(0, J0);
    int J1; int o1 = TILE_OFS(1, J1);
    btf = B8[o1]; bnf = B8[o1 + 2];                        // frags tile 1

    float acc = 0.0f;
    #pragma unroll 2
    for (int idx = 1; idx < total; ++idx) {
        // stage 1: MFMA for tile idx (frags loaded last iteration)
        f32x16 ct_n = __builtin_amdgcn_mfma_f32_32x32x16_bf16(at, btf, Z, 0, 0, 0);
        f32x16 cn_n = __builtin_amdgcn_mfma_f32_32x32x16_bf16(an, bnf, Z, 0, 0, 0);
        int Jc; float w_n = TILE_W(idx, (TILE_OFS(idx, Jc), Jc));   // uniform

        // stage 2: load frags for tile idx+1 (clamped redundant last)
        int nid = (idx + 1 < total) ? idx + 1 : idx;
        int Jn; int on = TILE_OFS(nid, Jn);
        btf = B8[on]; bnf = B8[on + 2];

        // stage 3: epilogue for tile idx-1 (overlaps MFMA/loads above)
        float ts0 = 0.0f, ts1 = 0.0f;
        #pragma unroll
        for (int gq = 0; gq < 4; ++gq) {
            float t0 = ct_p[4*gq+0], t1 = ct_p[4*gq+1], t2 = ct_p[4*gq+2], t3 = ct_p[4*gq+3];
            float q0 = t0*t0, q1 = t1*t1, q2 = t2*t2, q3 = t3*t3;
            float s01 = q0*q1, s23 = q2*q3;
            float r   = __builtin_amdgcn_rcpf(s01*s23);
            float u   = __builtin_fmaf(cn_p[4*gq+1], q0, cn_p[4*gq+0]*q1);
            float v   = __builtin_fmaf(cn_p[4*gq+3], q2, cn_p[4*gq+2]*q3);
            float num = __builtin_fmaf(v, s01, u*s23);
            if (gq & 1) ts1 = __builtin_fmaf(num, r, ts1);
            else        ts0 = __builtin_fmaf(num, r, ts0);
        }
        acc = __builtin_fmaf(w_p, ts0 + ts1, acc);

        ct_p = ct_n; cn_p = cn_n; w_p = w_n;               // SSA rotation (no movs)
    }

    // ---- pipeline drain: epilogue for the last tile ----
    {
        float ts0 = 0.0f, ts1 = 0.0f;
        #pragma unroll
        for (int gq = 0; gq < 4; ++gq) {
            float t0 = ct_p[4*gq+0], t1 = ct_p[4*gq+1], t2 = ct_p[4*gq+2], t3 = ct_p[4*gq+3];
            float q0 = t0*t0, q1 = t1*t1, q2 = t2*t2, q3 = t3*t3;
            float s01 = q0*q1, s23 = q2*q3;
            float r   = __builtin_amdgcn_rcpf(s01*s23);
            float u   = __builtin_fmaf(cn_p[4*gq+1], q0, cn_p[4*gq+0]*q1);
            float v   = __builtin_fmaf(cn_p[4*gq+3], q2, cn_p[4*gq+2]*q3);
            float num = __builtin_fmaf(v, s01, u*s23);
            if (gq & 1) ts1 = __builtin_fmaf(num, r, ts1);
            else        ts0 = __builtin_fmaf(num, r, ts0);
        }
        acc = __builtin_fmaf(w_p, ts0 + ts1, acc);
    }
    #undef TILE_OFS
    #undef TILE_W

    // wave shuffle reduce -> 4 partials -> one atomic per block
    for (int off = 32; off; off >>= 1) acc += __shfl_down(acc, off, 64);
    __shared__ float partial[4];
    if ((tid & 63) == 0) partial[wid] = acc;
    __syncthreads();
    if (tid == 0)
        atomicAdd(out, (partial[0] + partial[1]) + (partial[2] + partial[3]));
}

extern "C" void kernel_launch(void* const* d_in, const int* in_sizes, int n_in,
                              void* d_out, int out_size, void* d_ws, size_t ws_size,
                              hipStream_t stream) {
    const float* sv = (const float*)d_in[0];
    const int*   si = (const int*)d_in[1];
    const float* tv = (const float*)d_in[2];
    const int*   ti = (const int*)d_in[3];
    const float* rn = (const float*)d_in[4];
    const float* rc = (const float*)d_in[5];
    float* out = (float*)d_out;
    u16*   ws  = (u16*)d_ws;                      // 2 x 24576 x 64 B = 3 MB features

    setup_feats<<<2*NPTS/256, 256, 0, stream>>>(sv, si, tv, ti, rn, rc, ws, out);
    dim3 grid(NXB, NYG);                          // 192 x 13 = 2496 blocks of 256
    energy_mfma<<<grid, 256, 0, stream>>>(ws, out);
}